// Round 4
// baseline (1268.413 us; speedup 1.0000x reference)
//
#include <hip/hip_runtime.h>
#include <cstddef>
#include <cstdint>

typedef __attribute__((ext_vector_type(8))) short short8v;
typedef __attribute__((ext_vector_type(4))) short short4v;
typedef __attribute__((ext_vector_type(4))) float floatx4;

__device__ __forceinline__ float b2f(short u){
    return __uint_as_float(((unsigned)(unsigned short)u) << 16);
}
__device__ __forceinline__ short f2b(float f){
    unsigned x = __float_as_uint(f);
    unsigned r = x + 0x7FFFu + ((x >> 16) & 1u);
    return (short)(r >> 16);
}
__device__ __forceinline__ float loadF(const void* p, size_t i, int isBf16){
    return isBf16 ? b2f(((const short*)p)[i]) : ((const float*)p)[i];
}
__device__ __forceinline__ int loadI(const void* p, size_t i, int isI64){
    return isI64 ? ((const int*)p)[2 * i] : ((const int*)p)[i];
}

// flags: [0]=floats-bf16 [1]=ints-i64 [8..10]=B-hasLo per layer [12]=feat-hasLo [13]=const 1
__global__ void detect_kernel(const void* feat, const void* ei, int E, int* flags){
    int lane = threadIdx.x;
    if (lane >= 8 && lane < 16) flags[lane] = (lane == 13) ? 1 : 0;
    const unsigned short* fs = (const unsigned short*)feat;
    int plaus = 0;
    for (int j = lane; j < 128; j += 64){
        unsigned short s = fs[2 * j];
        int e = (s >> 7) & 0xFF;
        if (s == 0 || (e >= 100 && e <= 140)) plaus++;
    }
    #pragma unroll
    for (int o = 32; o > 0; o >>= 1) plaus += __shfl_xor(plaus, o);
    const int* ew = (const int*)ei;
    int zeros = 0;
    for (int j = lane; j < 128; j += 64) if (ew[2 * j + 1] == 0) zeros++;
    #pragma unroll
    for (int o = 32; o > 0; o >>= 1) zeros += __shfl_xor(zeros, o);
    if (lane == 0){ flags[0] = (plaus >= 64) ? 1 : 0; flags[1] = (zeros >= 64) ? 1 : 0; }
    (void)E;
}

__global__ void sentinel_kernel(void* out, const int* flags, float v){
    if (threadIdx.x == 0){
        if (flags[0]) ((short*)out)[0] = f2b(v);
        else          ((float*)out)[0] = v;
    }
}

// ---------------- preprocessing: CSR by dst ----------------
__global__ void zero3(int* cnt, int* fill, unsigned* pool, int N){
    int i = blockIdx.x * 256 + threadIdx.x;
    if (i < N){ cnt[i] = 0; fill[i] = 0; }
    if (i < 256) pool[i] = 0u;
}

__global__ void hist_kernel(const void* __restrict__ ei, int* __restrict__ cnt, int E,
                            const int* __restrict__ flags){
    int i = blockIdx.x * 256 + threadIdx.x;
    if (i < E) atomicAdd(&cnt[loadI(ei, (size_t)E + i, flags[1])], 1);
}

__global__ void scan_kernel(const int* __restrict__ cnt, int* __restrict__ off, int N){
    __shared__ int wsum[16];
    __shared__ int base;
    const int t = threadIdx.x;
    const int w = t >> 6, lane = t & 63;
    if (t == 0) base = 0;
    __syncthreads();
    for (int s = 0; s < N; s += 1024){
        int v = (s + t < N) ? cnt[s + t] : 0;
        int x = v;
        #pragma unroll
        for (int o = 1; o < 64; o <<= 1){
            int y = __shfl_up(x, o);
            if (lane >= o) x += y;
        }
        if (lane == 63) wsum[w] = x;
        __syncthreads();
        if (w == 0){
            int mv = (lane < 16) ? wsum[lane] : 0;
            int xx = mv;
            #pragma unroll
            for (int o = 1; o < 16; o <<= 1){
                int y = __shfl_up(xx, o);
                if (lane >= o) xx += y;
            }
            if (lane < 16) wsum[lane] = xx - mv;
        }
        __syncthreads();
        int incl = x + wsum[w] + base;
        if (s + t < N) off[s + t] = incl - v;
        __syncthreads();
        if (t == 1023) base = incl;
        __syncthreads();
    }
    if (t == 0) off[N] = base;
}

__global__ void scatter_kernel(const void* __restrict__ ei, const void* __restrict__ ea,
                               const int* __restrict__ off, int* __restrict__ fill,
                               int* __restrict__ srcS, float* __restrict__ eaS,
                               int E, const int* __restrict__ flags){
    int i = blockIdx.x * 256 + threadIdx.x;
    if (i >= E) return;
    int d = loadI(ei, (size_t)E + i, flags[1]);
    int pos = off[d] + atomicAdd(&fill[d], 1);
    srcS[pos] = loadI(ei, (size_t)i, flags[1]);
    eaS[pos] = loadF(ea, (size_t)i, flags[0]);
}

// W [K x 256] -> Bt hi/lo [ ... x K] at given base (concat offset applied by caller)
__global__ void prep_b(const void* __restrict__ W, short* __restrict__ bhi,
                       short* __restrict__ blo, int K, const int* __restrict__ flags,
                       int* __restrict__ hasLo){
    int idx = blockIdx.x * 256 + threadIdx.x;   // grid = K blocks
    int k = idx >> 8, c = idx & 255;
    float v = loadF(W, idx, flags[0]);
    short h = f2b(v);
    short l = f2b(v - b2f(h));
    bhi[(size_t)c * K + k] = h;
    blo[(size_t)c * K + k] = l;
    if (__ballot(l != 0) != 0ull && (threadIdx.x & 63) == 0) atomicOr(hasLo, 1);
}

// features -> hi/lo bf16 split (lo==0 & flag stays 0 when input already bf16)
__global__ void split_feat(const void* __restrict__ in, short* __restrict__ hi,
                           short* __restrict__ lo, int n4, const int* __restrict__ flags,
                           int* __restrict__ hasLo){
    int i = blockIdx.x * 256 + threadIdx.x;
    if (i >= n4) return;
    int fbf = flags[0];
    short4v h4, l4;
    int nz = 0;
    #pragma unroll
    for (int j = 0; j < 4; j++){
        float v = loadF(in, (size_t)i * 4 + j, fbf);
        short h = f2b(v);
        short l = f2b(v - b2f(h));
        h4[j] = h; l4[j] = l;
        nz |= (int)l;
    }
    *(short4v*)&hi[(size_t)i * 4] = h4;
    *(short4v*)&lo[(size_t)i * 4] = l4;
    if (__ballot(nz != 0) != 0ull && (threadIdx.x & 63) == 0) atomicOr(hasLo, 1);
}

// fused small-array decode: 13 jobs in one launch
struct DJob { const void* src; float* dst; int n; };
struct DJobs { DJob j[13]; };
__global__ void decode_many(DJobs jobs, const int* __restrict__ flags){
    const DJob J = jobs.j[blockIdx.x];
    int fbf = flags[0];
    for (int i = threadIdx.x; i < J.n; i += 256)
        J.dst[i] = loadF(J.src, (size_t)i, fbf);
}

// -------- fused-pair split GEMM: C[M x 512] = A[M x K] * Bt[512 x K]^T --------
// A,B as bf16 hi/lo pairs; 128x128 tile, 4 waves, XOR-swizzled LDS (T2).
__global__ __launch_bounds__(256) void gemm_pair(
        const short* __restrict__ Ahi, const short* __restrict__ Alo,
        const short* __restrict__ Bhi, const short* __restrict__ Blo,
        float* __restrict__ C, int M, int K,
        const int* __restrict__ aLoFlag, const int* __restrict__ bLoFlag){
    __shared__ __align__(16) short Ah[128 * 64];
    __shared__ __align__(16) short Al[128 * 64];
    __shared__ __align__(16) short Bh[128 * 64];
    __shared__ __align__(16) short Bl[128 * 64];
    const int t = threadIdx.x;
    const int w = t >> 6, lane = t & 63;
    const int wr = w >> 1, wc = w & 1;
    const int bRow = blockIdx.x * 128;
    const int bCol = blockIdx.y * 128;
    const int az = aLoFlag[0] ? 0 : 1;
    const int bz = bLoFlag[0] ? 0 : 1;

    floatx4 acc[4][4];
    #pragma unroll
    for (int m = 0; m < 4; m++)
        #pragma unroll
        for (int n = 0; n < 4; n++) acc[m][n] = (floatx4){0.f, 0.f, 0.f, 0.f};

    for (int k0 = 0; k0 < K; k0 += 64){
        // stage 128 rows x 64 cols per buffer; e-th 16B chunk: row=e>>3, chunk=e&7
        // swizzled LDS elem offset within row: ((chunk*16) ^ ((row&7)<<4)) >> 1
        #pragma unroll
        for (int i = 0; i < 4; i++){
            int e = i * 256 + t;
            int r = e >> 3, c = e & 7;
            int sw = (((c << 4) ^ ((r & 7) << 4)) >> 1);
            int gr = bRow + r; if (gr >= M) gr = M - 1;
            size_t ga = (size_t)gr * K + k0 + c * 8;
            *(short8v*)&Ah[r * 64 + sw] = *(const short8v*)&Ahi[ga];
            if (!az) *(short8v*)&Al[r * 64 + sw] = *(const short8v*)&Alo[ga];
            size_t gb = (size_t)(bCol + r) * K + k0 + c * 8;
            *(short8v*)&Bh[r * 64 + sw] = *(const short8v*)&Bhi[gb];
            if (!bz) *(short8v*)&Bl[r * 64 + sw] = *(const short8v*)&Blo[gb];
        }
        __syncthreads();
        #pragma unroll
        for (int ks = 0; ks < 2; ks++){
            short8v a_h[4], a_l[4], b_h[4], b_l[4];
            #pragma unroll
            for (int m = 0; m < 4; m++){
                int ar = wr * 64 + m * 16 + (lane & 15);
                int co = (((ks * 64 + ((lane >> 4) << 4)) ^ ((ar & 7) << 4)) >> 1);
                a_h[m] = *(const short8v*)&Ah[ar * 64 + co];
                if (!az) a_l[m] = *(const short8v*)&Al[ar * 64 + co];
            }
            #pragma unroll
            for (int n = 0; n < 4; n++){
                int br = wc * 64 + n * 16 + (lane & 15);
                int co = (((ks * 64 + ((lane >> 4) << 4)) ^ ((br & 7) << 4)) >> 1);
                b_h[n] = *(const short8v*)&Bh[br * 64 + co];
                if (!bz) b_l[n] = *(const short8v*)&Bl[br * 64 + co];
            }
            #pragma unroll
            for (int m = 0; m < 4; m++)
                #pragma unroll
                for (int n = 0; n < 4; n++){
                    if (!az) acc[m][n] = __builtin_amdgcn_mfma_f32_16x16x32_bf16(
                                             a_l[m], b_h[n], acc[m][n], 0, 0, 0);
                    if (!bz) acc[m][n] = __builtin_amdgcn_mfma_f32_16x16x32_bf16(
                                             a_h[m], b_l[n], acc[m][n], 0, 0, 0);
                    acc[m][n] = __builtin_amdgcn_mfma_f32_16x16x32_bf16(
                                    a_h[m], b_h[n], acc[m][n], 0, 0, 0);
                }
        }
        __syncthreads();
    }
    #pragma unroll
    for (int m = 0; m < 4; m++){
        int rb = bRow + wr * 64 + m * 16 + ((lane >> 4) << 2);
        #pragma unroll
        for (int n = 0; n < 4; n++){
            int cg = bCol + wc * 64 + n * 16 + (lane & 15);
            #pragma unroll
            for (int r = 0; r < 4; r++){
                int gr = rb + r;
                if (gr < M) C[(size_t)gr * 512 + cg] = acc[m][n][r];
            }
        }
    }
}

// ------- fused per-node: scores + online softmax + aggregation + bias + relu -------
// reads xl/xr from PR[M][512]; writes activation as bf16 hi/lo pair
__global__ __launch_bounds__(256) void fused_agg(const float* __restrict__ PR,
        const int* __restrict__ srcS, const float* __restrict__ eaS,
        const int* __restrict__ off, const float* __restrict__ WeF,
        const float* __restrict__ attF, const float* __restrict__ bbF,
        short* __restrict__ QHi, short* __restrict__ QLo, int N){
    int node = blockIdx.x * 4 + (threadIdx.x >> 6);
    int lane = threadIdx.x & 63;
    if (node >= N) return;
    const int beg = off[node], end = off[node + 1];
    const int dd = lane << 2;
    const floatx4 xr4 = *(const floatx4*)&PR[(size_t)node * 512 + 256 + dd];
    const floatx4 we4 = *(const floatx4*)&WeF[dd];
    const floatx4 at4 = *(const floatx4*)&attF[dd];
    float m = -1e30f, ssum = 0.f;
    floatx4 a4 = (floatx4){0.f, 0.f, 0.f, 0.f};
    for (int k0 = beg; k0 < end; k0 += 8){
        floatx4 v[8]; float pp[8]; float eav[8];
        #pragma unroll
        for (int c = 0; c < 8; c++){
            int k = k0 + c; if (k >= end) k = end - 1;
            int s = srcS[k];
            eav[c] = eaS[k];
            v[c] = *(const floatx4*)&PR[(size_t)s * 512 + dd];
        }
        #pragma unroll
        for (int c = 0; c < 8; c++){
            float p = 0.f;
            #pragma unroll
            for (int j = 0; j < 4; j++){
                float tv = v[c][j] + xr4[j] + eav[c] * we4[j];
                tv = tv > 0.f ? tv : 0.2f * tv;
                p += tv * at4[j];
            }
            #pragma unroll
            for (int o = 32; o > 0; o >>= 1) p += __shfl_xor(p, o);
            pp[c] = (k0 + c < end) ? p : -1e30f;
        }
        float pm = pp[0];
        #pragma unroll
        for (int c = 1; c < 8; c++) pm = fmaxf(pm, pp[c]);
        float newm = fmaxf(m, pm);
        float scale = __expf(m - newm);
        ssum *= scale;
        a4[0] *= scale; a4[1] *= scale; a4[2] *= scale; a4[3] *= scale;
        #pragma unroll
        for (int c = 0; c < 8; c++){
            float wgt = __expf(pp[c] - newm);
            ssum += wgt;
            a4[0] += wgt * v[c][0]; a4[1] += wgt * v[c][1];
            a4[2] += wgt * v[c][2]; a4[3] += wgt * v[c][3];
        }
        m = newm;
    }
    float inv = (end > beg) ? 1.f / ssum : 0.f;
    short4v h4, l4;
    #pragma unroll
    for (int j = 0; j < 4; j++){
        float o = fmaxf(a4[j] * inv + bbF[dd + j], 0.f);
        short h = f2b(o);
        h4[j] = h;
        l4[j] = f2b(o - b2f(h));
    }
    *(short4v*)&QHi[(size_t)node * 256 + dd] = h4;
    *(short4v*)&QLo[(size_t)node * 256 + dd] = l4;
}

// ---------------- global max pool over hi/lo activation ----------------
__global__ __launch_bounds__(256) void col_max2(const short* __restrict__ hi,
        const short* __restrict__ lo, unsigned* __restrict__ pool, int N){
    int lane = threadIdx.x & 63;
    int w = threadIdx.x >> 6;
    int dd = lane << 2;
    floatx4 mx = (floatx4){0.f, 0.f, 0.f, 0.f};
    for (int r = blockIdx.x * 4 + w; r < N; r += gridDim.x * 4){
        short4v h = *(const short4v*)&hi[(size_t)r * 256 + dd];
        short4v l = *(const short4v*)&lo[(size_t)r * 256 + dd];
        mx[0] = fmaxf(mx[0], b2f(h[0]) + b2f(l[0]));
        mx[1] = fmaxf(mx[1], b2f(h[1]) + b2f(l[1]));
        mx[2] = fmaxf(mx[2], b2f(h[2]) + b2f(l[2]));
        mx[3] = fmaxf(mx[3], b2f(h[3]) + b2f(l[3]));
    }
    atomicMax(&pool[dd + 0], __float_as_uint(mx[0]));
    atomicMax(&pool[dd + 1], __float_as_uint(mx[1]));
    atomicMax(&pool[dd + 2], __float_as_uint(mx[2]));
    atomicMax(&pool[dd + 3], __float_as_uint(mx[3]));
}

__global__ void head_kernel(const unsigned* __restrict__ pool, const float* __restrict__ Wh1F,
        const float* __restrict__ bh1F, const float* __restrict__ Wh2F,
        const float* __restrict__ bh2F, void* __restrict__ out, const int* __restrict__ flags){
    int lane = threadIdx.x;
    float acc = 0.f;
    if (lane < 10){
        acc = bh1F[lane];
        for (int d = 0; d < 256; ++d)
            acc += __uint_as_float(pool[d]) * Wh1F[d * 10 + lane];
        acc = fmaxf(acc, 0.f) * Wh2F[lane];
    }
    #pragma unroll
    for (int o = 32; o > 0; o >>= 1) acc += __shfl_xor(acc, o);
    if (lane == 0){
        float r = acc + bh2F[0];
        if (flags[0]) ((short*)out)[0] = f2b(r);
        else          ((float*)out)[0] = r;
    }
}

extern "C" void kernel_launch(void* const* d_in, const int* in_sizes, int n_in,
                              void* d_out, int out_size, void* d_ws, size_t ws_size,
                              hipStream_t stream){
    const void* feat = d_in[0];
    const void* ei   = d_in[1];
    const void* ea   = d_in[2];
    const void* Wl[3] = {d_in[3], d_in[8],  d_in[13]};
    const void* Wr[3] = {d_in[4], d_in[9],  d_in[14]};
    const void* We[3] = {d_in[5], d_in[10], d_in[15]};
    const void* at[3] = {d_in[6], d_in[11], d_in[16]};
    const void* bb[3] = {d_in[7], d_in[12], d_in[17]};
    const void* Wh1 = d_in[18];
    const void* bh1 = d_in[19];
    const void* Wh2 = d_in[20];
    const void* bh2 = d_in[21];

    const int N = in_sizes[0] / 128;
    const int E = in_sizes[1] / 2;
    const int Kin[3] = {128, 256, 256};

    char* p = (char*)d_ws;
    auto alloc = [&](size_t bytes) -> void* {
        void* r = (void*)p; p += (bytes + 255) & ~(size_t)255; return r;
    };
    int*   flags = (int*)alloc(256);
    int*   off   = (int*)alloc((size_t)(N + 1) * 4);
    int*   cnt   = (int*)alloc((size_t)N * 4);
    int*   fill  = (int*)alloc((size_t)N * 4);
    int*   srcS  = (int*)alloc((size_t)E * 4);
    float* eaS   = (float*)alloc((size_t)E * 4);
    float* PR    = (float*)alloc((size_t)N * 512 * 4);
    short* QHi   = (short*)alloc((size_t)N * 256 * 2);   // first half doubles as featHi
    short* QLo   = (short*)alloc((size_t)N * 256 * 2);   // first half doubles as featLo
    short* BtH[3]; short* BtL[3];
    for (int i = 0; i < 3; i++){
        BtH[i] = (short*)alloc((size_t)512 * Kin[i] * 2);
        BtL[i] = (short*)alloc((size_t)512 * Kin[i] * 2);
    }
    float* WeF  = (float*)alloc(3 * 256 * 4);
    float* attF = (float*)alloc(3 * 256 * 4);
    float* bbF  = (float*)alloc(3 * 256 * 4);
    float* Wh1F = (float*)alloc(2560 * 4);
    float* bh1F = (float*)alloc(16 * 4);
    float* Wh2F = (float*)alloc(16 * 4);
    float* bh2F = (float*)alloc(4 * 4);
    unsigned* pool = (unsigned*)alloc(256 * 4);
    size_t need = (size_t)(p - (char*)d_ws);

    detect_kernel<<<dim3(1), dim3(64), 0, stream>>>(feat, ei, E, flags);
    sentinel_kernel<<<dim3(1), dim3(1), 0, stream>>>(d_out, flags, 777.0f);
    if (need > ws_size){
        sentinel_kernel<<<dim3(1), dim3(1), 0, stream>>>(d_out, flags, 555.0f);
        return;
    }

    zero3<<<dim3((N + 255) / 256), dim3(256), 0, stream>>>(cnt, fill, pool, N);
    hist_kernel<<<dim3((E + 255) / 256), dim3(256), 0, stream>>>(ei, cnt, E, flags);
    scan_kernel<<<dim3(1), dim3(1024), 0, stream>>>(cnt, off, N);
    scatter_kernel<<<dim3((E + 255) / 256), dim3(256), 0, stream>>>(ei, ea, off, fill,
                                                                    srcS, eaS, E, flags);
    // weights: concat [Wl ; Wr] -> Bt[512 x K] hi/lo
    for (int i = 0; i < 3; i++){
        prep_b<<<dim3(Kin[i]), dim3(256), 0, stream>>>(Wl[i], BtH[i], BtL[i],
                                                       Kin[i], flags, &flags[8 + i]);
        prep_b<<<dim3(Kin[i]), dim3(256), 0, stream>>>(Wr[i], BtH[i] + (size_t)256 * Kin[i],
                                                       BtL[i] + (size_t)256 * Kin[i],
                                                       Kin[i], flags, &flags[8 + i]);
    }
    split_feat<<<dim3((N * 128 / 4 + 255) / 256), dim3(256), 0, stream>>>(
        feat, QHi, QLo, N * 128 / 4, flags, &flags[12]);
    DJobs jobs;
    for (int i = 0; i < 3; i++){
        jobs.j[i]     = { We[i], WeF  + i * 256, 256 };
        jobs.j[3 + i] = { at[i], attF + i * 256, 256 };
        jobs.j[6 + i] = { bb[i], bbF  + i * 256, 256 };
    }
    jobs.j[9]  = { Wh1, Wh1F, 2560 };
    jobs.j[10] = { bh1, bh1F, 10 };
    jobs.j[11] = { Wh2, Wh2F, 10 };
    jobs.j[12] = { bh2, bh2F, 1 };
    decode_many<<<dim3(13), dim3(256), 0, stream>>>(jobs, flags);

    dim3 gemm_grid((N + 127) / 128, 4);
    for (int L = 0; L < 3; L++){
        const int* aflag = (L == 0) ? &flags[12] : &flags[13];
        gemm_pair<<<gemm_grid, dim3(256), 0, stream>>>(QHi, QLo, BtH[L], BtL[L],
                                                       PR, N, Kin[L], aflag, &flags[8 + L]);
        fused_agg<<<dim3((N + 3) / 4), dim3(256), 0, stream>>>(PR, srcS, eaS, off,
                                                               WeF + L * 256, attF + L * 256,
                                                               bbF + L * 256, QHi, QLo, N);
    }
    col_max2<<<dim3(256), dim3(256), 0, stream>>>(QHi, QLo, pool, N);
    head_kernel<<<dim3(1), dim3(64), 0, stream>>>(pool, Wh1F, bh1F, Wh2F, bh2F, d_out, flags);
    (void)n_in; (void)out_size;
}

// Round 5
// 861.545 us; speedup vs baseline: 1.4723x; 1.4723x over previous
//
#include <hip/hip_runtime.h>
#include <cstddef>
#include <cstdint>

typedef __attribute__((ext_vector_type(8))) short short8v;
typedef __attribute__((ext_vector_type(4))) short short4v;
typedef __attribute__((ext_vector_type(4))) float floatx4;

__device__ __forceinline__ float b2f(short u){
    return __uint_as_float(((unsigned)(unsigned short)u) << 16);
}
__device__ __forceinline__ short f2b(float f){
    unsigned x = __float_as_uint(f);
    unsigned r = x + 0x7FFFu + ((x >> 16) & 1u);
    return (short)(r >> 16);
}
__device__ __forceinline__ float loadF(const void* p, size_t i, int isBf16){
    return isBf16 ? b2f(((const short*)p)[i]) : ((const float*)p)[i];
}
__device__ __forceinline__ int loadI(const void* p, size_t i, int isI64){
    return isI64 ? ((const int*)p)[2 * i] : ((const int*)p)[i];
}

// flags: [0]=floats-bf16 [1]=ints-i64 [8..10]=B-hasLo per layer
__global__ void detect_kernel(const void* feat, const void* ei, int E, int* flags){
    int lane = threadIdx.x;
    if (lane >= 8 && lane < 16) flags[lane] = 0;
    const unsigned short* fs = (const unsigned short*)feat;
    int plaus = 0;
    for (int j = lane; j < 128; j += 64){
        unsigned short s = fs[2 * j];
        int e = (s >> 7) & 0xFF;
        if (s == 0 || (e >= 100 && e <= 140)) plaus++;
    }
    #pragma unroll
    for (int o = 32; o > 0; o >>= 1) plaus += __shfl_xor(plaus, o);
    const int* ew = (const int*)ei;
    int zeros = 0;
    for (int j = lane; j < 128; j += 64) if (ew[2 * j + 1] == 0) zeros++;
    #pragma unroll
    for (int o = 32; o > 0; o >>= 1) zeros += __shfl_xor(zeros, o);
    if (lane == 0){ flags[0] = (plaus >= 64) ? 1 : 0; flags[1] = (zeros >= 64) ? 1 : 0; }
    (void)E;
}

__global__ void sentinel_kernel(void* out, const int* flags, float v){
    if (threadIdx.x == 0){
        if (flags[0]) ((short*)out)[0] = f2b(v);
        else          ((float*)out)[0] = v;
    }
}

// ---------------- preprocessing: CSR by dst ----------------
__global__ void zero3(int* cnt, int* fill, unsigned* pool, int N){
    int i = blockIdx.x * 256 + threadIdx.x;
    if (i < N){ cnt[i] = 0; fill[i] = 0; }
    if (i < 256) pool[i] = 0u;
}

__global__ void hist_kernel(const void* __restrict__ ei, int* __restrict__ cnt, int E,
                            const int* __restrict__ flags){
    int i = blockIdx.x * 256 + threadIdx.x;
    if (i < E) atomicAdd(&cnt[loadI(ei, (size_t)E + i, flags[1])], 1);
}

// ---- 3-phase scan: per-block scan -> scan of block totals -> add offsets ----
__global__ void scanA(const int* __restrict__ cnt, int* __restrict__ off,
                      int* __restrict__ partial, int N){
    __shared__ int wsum[16];
    const int t = threadIdx.x, w = t >> 6, lane = t & 63;
    int i = blockIdx.x * 1024 + t;
    int v = (i < N) ? cnt[i] : 0;
    int x = v;
    #pragma unroll
    for (int o = 1; o < 64; o <<= 1){
        int y = __shfl_up(x, o);
        if (lane >= o) x += y;
    }
    if (lane == 63) wsum[w] = x;
    __syncthreads();
    if (w == 0){
        int mv = (lane < 16) ? wsum[lane] : 0;
        int xx = mv;
        #pragma unroll
        for (int o = 1; o < 16; o <<= 1){
            int y = __shfl_up(xx, o);
            if (lane >= o) xx += y;
        }
        if (lane < 16) wsum[lane] = xx - mv;   // exclusive wave offsets
    }
    __syncthreads();
    int incl = x + wsum[w];
    if (i < N) off[i] = incl - v;              // block-local exclusive
    if (t == 1023) partial[blockIdx.x] = incl; // block total
}

__global__ void scanB(int* __restrict__ partial, int* __restrict__ off, int nb, int N){
    int lane = threadIdx.x;                    // 64 threads, nb <= 64
    int v = (lane < nb) ? partial[lane] : 0;
    int x = v;
    #pragma unroll
    for (int o = 1; o < 64; o <<= 1){
        int y = __shfl_up(x, o);
        if (lane >= o) x += y;
    }
    if (lane < nb) partial[lane] = x - v;      // exclusive
    if (lane == 63) off[N] = x;                // grand total == E
}

__global__ void scanC(int* __restrict__ off, const int* __restrict__ partial, int N){
    int i = blockIdx.x * 1024 + threadIdx.x;
    if (i < N) off[i] += partial[blockIdx.x];
}

__global__ void scatter_kernel(const void* __restrict__ ei, const void* __restrict__ ea,
                               const int* __restrict__ off, int* __restrict__ fill,
                               int* __restrict__ srcS, float* __restrict__ eaS,
                               int E, const int* __restrict__ flags){
    int i = blockIdx.x * 256 + threadIdx.x;
    if (i >= E) return;
    int d = loadI(ei, (size_t)E + i, flags[1]);
    int pos = off[d] + atomicAdd(&fill[d], 1);
    srcS[pos] = loadI(ei, (size_t)i, flags[1]);
    eaS[pos] = loadF(ea, (size_t)i, flags[0]);
}

// W [K x 256] -> Bt hi/lo [... x K] at given base (concat offset applied by caller)
__global__ void prep_b(const void* __restrict__ W, short* __restrict__ bhi,
                       short* __restrict__ blo, int K, const int* __restrict__ flags,
                       int* __restrict__ hasLo){
    int idx = blockIdx.x * 256 + threadIdx.x;   // grid = K blocks
    int k = idx >> 8, c = idx & 255;
    float v = loadF(W, idx, flags[0]);
    short h = f2b(v);
    short l = f2b(v - b2f(h));
    bhi[(size_t)c * K + k] = h;
    blo[(size_t)c * K + k] = l;
    if (__ballot(l != 0) != 0ull && (threadIdx.x & 63) == 0) atomicOr(hasLo, 1);
}

// fused small-array decode: 13 jobs in one launch
struct DJob { const void* src; float* dst; int n; };
struct DJobs { DJob j[13]; };
__global__ void decode_many(DJobs jobs, const int* __restrict__ flags){
    const DJob J = jobs.j[blockIdx.x];
    int fbf = flags[0];
    for (int i = threadIdx.x; i < J.n; i += 256)
        J.dst[i] = loadF(J.src, (size_t)i, fbf);
}

// -------- fused-pair split GEMM: C[M x 512] = A[M x K] * Bt[512 x K]^T --------
// BZ=1: B-lo structurally zero (bf16 weights) - 3 LDS buffers, 3 blocks/CU.
// BZ=0: insurance path for f32 weights. Each variant early-exits unless the
// device-side bHasLo flag selects it.
template<int BZ>
__global__ __launch_bounds__(256, 3) void gemm_tpl(
        const void* __restrict__ A, const short* __restrict__ Alo, int aRaw,
        const short* __restrict__ Bhi, const short* __restrict__ Blo,
        float* __restrict__ C, int M, int K,
        const int* __restrict__ flags, const int* __restrict__ bLoFlag){
    if (BZ ? (bLoFlag[0] != 0) : (bLoFlag[0] == 0)) return;
    __shared__ __align__(16) short Ah[128 * 64];
    __shared__ __align__(16) short Al[128 * 64];
    __shared__ __align__(16) short Bh[128 * 64];
    __shared__ __align__(16) short Bl[BZ ? 8 : 128 * 64];
    const int fbf = flags[0];
    const int az = (aRaw && fbf) ? 1 : 0;   // A-lo structurally zero (raw bf16 A)
    const int t = threadIdx.x;
    const int w = t >> 6, lane = t & 63;
    const int wr = w >> 1, wc = w & 1;
    const int bRow = blockIdx.x * 128;
    const int bCol = blockIdx.y * 128;

    floatx4 acc[4][4];
    #pragma unroll
    for (int m = 0; m < 4; m++)
        #pragma unroll
        for (int n = 0; n < 4; n++) acc[m][n] = (floatx4){0.f, 0.f, 0.f, 0.f};

    for (int k0 = 0; k0 < K; k0 += 64){
        // stage 128 rows x 64 cols; chunk = 16B; swizzle: byte ^= (row&7)<<4
        #pragma unroll
        for (int i = 0; i < 4; i++){
            int e = i * 256 + t;
            int r = e >> 3, c = e & 7;
            int sw = (((c << 4) ^ ((r & 7) << 4)) >> 1);
            int gr = bRow + r; if (gr >= M) gr = M - 1;
            size_t ga = (size_t)gr * K + k0 + c * 8;
            if (aRaw){
                if (fbf){
                    *(short8v*)&Ah[r * 64 + sw] = *(const short8v*)&((const short*)A)[ga];
                } else {
                    const float* Af = (const float*)A;
                    floatx4 v0 = *(const floatx4*)&Af[ga];
                    floatx4 v1 = *(const floatx4*)&Af[ga + 4];
                    short8v h, l;
                    #pragma unroll
                    for (int j = 0; j < 4; j++){
                        short hj = f2b(v0[j]);
                        h[j] = hj; l[j] = f2b(v0[j] - b2f(hj));
                        short hk = f2b(v1[j]);
                        h[4 + j] = hk; l[4 + j] = f2b(v1[j] - b2f(hk));
                    }
                    *(short8v*)&Ah[r * 64 + sw] = h;
                    *(short8v*)&Al[r * 64 + sw] = l;
                }
            } else {
                *(short8v*)&Ah[r * 64 + sw] = *(const short8v*)&((const short*)A)[ga];
                *(short8v*)&Al[r * 64 + sw] = *(const short8v*)&Alo[ga];
            }
            size_t gb = (size_t)(bCol + r) * K + k0 + c * 8;
            *(short8v*)&Bh[r * 64 + sw] = *(const short8v*)&Bhi[gb];
            if (!BZ) *(short8v*)&Bl[r * 64 + sw] = *(const short8v*)&Blo[gb];
        }
        __syncthreads();
        #pragma unroll
        for (int ks = 0; ks < 2; ks++){
            short8v a_h[4], a_l[4], b_h[4], b_l[4];
            #pragma unroll
            for (int m = 0; m < 4; m++){
                int ar = wr * 64 + m * 16 + (lane & 15);
                int co = (((ks * 64 + ((lane >> 4) << 4)) ^ ((ar & 7) << 4)) >> 1);
                a_h[m] = *(const short8v*)&Ah[ar * 64 + co];
                if (!az) a_l[m] = *(const short8v*)&Al[ar * 64 + co];
            }
            #pragma unroll
            for (int n = 0; n < 4; n++){
                int br = wc * 64 + n * 16 + (lane & 15);
                int co = (((ks * 64 + ((lane >> 4) << 4)) ^ ((br & 7) << 4)) >> 1);
                b_h[n] = *(const short8v*)&Bh[br * 64 + co];
                if (!BZ) b_l[n] = *(const short8v*)&Bl[br * 64 + co];
            }
            #pragma unroll
            for (int m = 0; m < 4; m++)
                #pragma unroll
                for (int n = 0; n < 4; n++){
                    if (!az) acc[m][n] = __builtin_amdgcn_mfma_f32_16x16x32_bf16(
                                             a_l[m], b_h[n], acc[m][n], 0, 0, 0);
                    if (!BZ) acc[m][n] = __builtin_amdgcn_mfma_f32_16x16x32_bf16(
                                             a_h[m], b_l[n], acc[m][n], 0, 0, 0);
                    acc[m][n] = __builtin_amdgcn_mfma_f32_16x16x32_bf16(
                                    a_h[m], b_h[n], acc[m][n], 0, 0, 0);
                }
        }
        __syncthreads();
    }
    #pragma unroll
    for (int m = 0; m < 4; m++){
        int rb = bRow + wr * 64 + m * 16 + ((lane >> 4) << 2);
        #pragma unroll
        for (int n = 0; n < 4; n++){
            int cg = bCol + wc * 64 + n * 16 + (lane & 15);
            #pragma unroll
            for (int r = 0; r < 4; r++){
                int gr = rb + r;
                if (gr < M) C[(size_t)gr * 512 + cg] = acc[m][n][r];
            }
        }
    }
}

// ------- fused per-node: scores + online softmax + aggregation + bias + relu -------
// reads xl/xr from PR[M][512]; writes activation as bf16 hi/lo pair
__global__ __launch_bounds__(256) void fused_agg(const float* __restrict__ PR,
        const int* __restrict__ srcS, const float* __restrict__ eaS,
        const int* __restrict__ off, const float* __restrict__ WeF,
        const float* __restrict__ attF, const float* __restrict__ bbF,
        short* __restrict__ QHi, short* __restrict__ QLo, int N){
    int node = blockIdx.x * 4 + (threadIdx.x >> 6);
    int lane = threadIdx.x & 63;
    if (node >= N) return;
    const int beg = off[node], end = off[node + 1];
    const int dd = lane << 2;
    const floatx4 xr4 = *(const floatx4*)&PR[(size_t)node * 512 + 256 + dd];
    const floatx4 we4 = *(const floatx4*)&WeF[dd];
    const floatx4 at4 = *(const floatx4*)&attF[dd];
    float m = -1e30f, ssum = 0.f;
    floatx4 a4 = (floatx4){0.f, 0.f, 0.f, 0.f};
    for (int k0 = beg; k0 < end; k0 += 8){
        floatx4 v[8]; float pp[8]; float eav[8];
        #pragma unroll
        for (int c = 0; c < 8; c++){
            int k = k0 + c; if (k >= end) k = end - 1;
            int s = srcS[k];
            eav[c] = eaS[k];
            v[c] = *(const floatx4*)&PR[(size_t)s * 512 + dd];
        }
        #pragma unroll
        for (int c = 0; c < 8; c++){
            float p = 0.f;
            #pragma unroll
            for (int j = 0; j < 4; j++){
                float tv = v[c][j] + xr4[j] + eav[c] * we4[j];
                tv = tv > 0.f ? tv : 0.2f * tv;
                p += tv * at4[j];
            }
            #pragma unroll
            for (int o = 32; o > 0; o >>= 1) p += __shfl_xor(p, o);
            pp[c] = (k0 + c < end) ? p : -1e30f;
        }
        float pm = pp[0];
        #pragma unroll
        for (int c = 1; c < 8; c++) pm = fmaxf(pm, pp[c]);
        float newm = fmaxf(m, pm);
        float scale = __expf(m - newm);
        ssum *= scale;
        a4[0] *= scale; a4[1] *= scale; a4[2] *= scale; a4[3] *= scale;
        #pragma unroll
        for (int c = 0; c < 8; c++){
            float wgt = __expf(pp[c] - newm);
            ssum += wgt;
            a4[0] += wgt * v[c][0]; a4[1] += wgt * v[c][1];
            a4[2] += wgt * v[c][2]; a4[3] += wgt * v[c][3];
        }
        m = newm;
    }
    float inv = (end > beg) ? 1.f / ssum : 0.f;
    short4v h4, l4;
    #pragma unroll
    for (int j = 0; j < 4; j++){
        float o = fmaxf(a4[j] * inv + bbF[dd + j], 0.f);
        short h = f2b(o);
        h4[j] = h;
        l4[j] = f2b(o - b2f(h));
    }
    *(short4v*)&QHi[(size_t)node * 256 + dd] = h4;
    *(short4v*)&QLo[(size_t)node * 256 + dd] = l4;
}

// ---------------- global max pool over hi/lo activation ----------------
__global__ __launch_bounds__(256) void col_max2(const short* __restrict__ hi,
        const short* __restrict__ lo, unsigned* __restrict__ pool, int N){
    int lane = threadIdx.x & 63;
    int w = threadIdx.x >> 6;
    int dd = lane << 2;
    floatx4 mx = (floatx4){0.f, 0.f, 0.f, 0.f};
    for (int r = blockIdx.x * 4 + w; r < N; r += gridDim.x * 4){
        short4v h = *(const short4v*)&hi[(size_t)r * 256 + dd];
        short4v l = *(const short4v*)&lo[(size_t)r * 256 + dd];
        mx[0] = fmaxf(mx[0], b2f(h[0]) + b2f(l[0]));
        mx[1] = fmaxf(mx[1], b2f(h[1]) + b2f(l[1]));
        mx[2] = fmaxf(mx[2], b2f(h[2]) + b2f(l[2]));
        mx[3] = fmaxf(mx[3], b2f(h[3]) + b2f(l[3]));
    }
    atomicMax(&pool[dd + 0], __float_as_uint(mx[0]));
    atomicMax(&pool[dd + 1], __float_as_uint(mx[1]));
    atomicMax(&pool[dd + 2], __float_as_uint(mx[2]));
    atomicMax(&pool[dd + 3], __float_as_uint(mx[3]));
}

__global__ void head_kernel(const unsigned* __restrict__ pool, const float* __restrict__ Wh1F,
        const float* __restrict__ bh1F, const float* __restrict__ Wh2F,
        const float* __restrict__ bh2F, void* __restrict__ out, const int* __restrict__ flags){
    int lane = threadIdx.x;
    float acc = 0.f;
    if (lane < 10){
        acc = bh1F[lane];
        for (int d = 0; d < 256; ++d)
            acc += __uint_as_float(pool[d]) * Wh1F[d * 10 + lane];
        acc = fmaxf(acc, 0.f) * Wh2F[lane];
    }
    #pragma unroll
    for (int o = 32; o > 0; o >>= 1) acc += __shfl_xor(acc, o);
    if (lane == 0){
        float r = acc + bh2F[0];
        if (flags[0]) ((short*)out)[0] = f2b(r);
        else          ((float*)out)[0] = r;
    }
}

extern "C" void kernel_launch(void* const* d_in, const int* in_sizes, int n_in,
                              void* d_out, int out_size, void* d_ws, size_t ws_size,
                              hipStream_t stream){
    const void* feat = d_in[0];
    const void* ei   = d_in[1];
    const void* ea   = d_in[2];
    const void* Wl[3] = {d_in[3], d_in[8],  d_in[13]};
    const void* Wr[3] = {d_in[4], d_in[9],  d_in[14]};
    const void* We[3] = {d_in[5], d_in[10], d_in[15]};
    const void* at[3] = {d_in[6], d_in[11], d_in[16]};
    const void* bb[3] = {d_in[7], d_in[12], d_in[17]};
    const void* Wh1 = d_in[18];
    const void* bh1 = d_in[19];
    const void* Wh2 = d_in[20];
    const void* bh2 = d_in[21];

    const int N = in_sizes[0] / 128;
    const int E = in_sizes[1] / 2;
    const int Kin[3] = {128, 256, 256};
    const int nb = (N + 1023) / 1024;

    char* p = (char*)d_ws;
    auto alloc = [&](size_t bytes) -> void* {
        void* r = (void*)p; p += (bytes + 255) & ~(size_t)255; return r;
    };
    int*   flags   = (int*)alloc(256);
    int*   partial = (int*)alloc(256 * 4);
    int*   off   = (int*)alloc((size_t)(N + 1) * 4);
    int*   cnt   = (int*)alloc((size_t)N * 4);
    int*   fill  = (int*)alloc((size_t)N * 4);
    int*   srcS  = (int*)alloc((size_t)E * 4);
    float* eaS   = (float*)alloc((size_t)E * 4);
    float* PR    = (float*)alloc((size_t)N * 512 * 4);
    short* QHi   = (short*)alloc((size_t)N * 256 * 2);
    short* QLo   = (short*)alloc((size_t)N * 256 * 2);
    short* BtH[3]; short* BtL[3];
    for (int i = 0; i < 3; i++){
        BtH[i] = (short*)alloc((size_t)512 * Kin[i] * 2);
        BtL[i] = (short*)alloc((size_t)512 * Kin[i] * 2);
    }
    float* WeF  = (float*)alloc(3 * 256 * 4);
    float* attF = (float*)alloc(3 * 256 * 4);
    float* bbF  = (float*)alloc(3 * 256 * 4);
    float* Wh1F = (float*)alloc(2560 * 4);
    float* bh1F = (float*)alloc(16 * 4);
    float* Wh2F = (float*)alloc(16 * 4);
    float* bh2F = (float*)alloc(4 * 4);
    unsigned* pool = (unsigned*)alloc(256 * 4);
    size_t need = (size_t)(p - (char*)d_ws);

    detect_kernel<<<dim3(1), dim3(64), 0, stream>>>(feat, ei, E, flags);
    sentinel_kernel<<<dim3(1), dim3(1), 0, stream>>>(d_out, flags, 777.0f);
    if (need > ws_size){
        sentinel_kernel<<<dim3(1), dim3(1), 0, stream>>>(d_out, flags, 555.0f);
        return;
    }

    zero3<<<dim3((N + 255) / 256), dim3(256), 0, stream>>>(cnt, fill, pool, N);
    hist_kernel<<<dim3((E + 255) / 256), dim3(256), 0, stream>>>(ei, cnt, E, flags);
    scanA<<<dim3(nb), dim3(1024), 0, stream>>>(cnt, off, partial, N);
    scanB<<<dim3(1), dim3(64), 0, stream>>>(partial, off, nb, N);
    scanC<<<dim3(nb), dim3(1024), 0, stream>>>(off, partial, N);
    scatter_kernel<<<dim3((E + 255) / 256), dim3(256), 0, stream>>>(ei, ea, off, fill,
                                                                    srcS, eaS, E, flags);
    // weights: concat [Wl ; Wr] -> Bt[512 x K] hi/lo
    for (int i = 0; i < 3; i++){
        prep_b<<<dim3(Kin[i]), dim3(256), 0, stream>>>(Wl[i], BtH[i], BtL[i],
                                                       Kin[i], flags, &flags[8 + i]);
        prep_b<<<dim3(Kin[i]), dim3(256), 0, stream>>>(Wr[i], BtH[i] + (size_t)256 * Kin[i],
                                                       BtL[i] + (size_t)256 * Kin[i],
                                                       Kin[i], flags, &flags[8 + i]);
    }
    DJobs jobs;
    for (int i = 0; i < 3; i++){
        jobs.j[i]     = { We[i], WeF  + i * 256, 256 };
        jobs.j[3 + i] = { at[i], attF + i * 256, 256 };
        jobs.j[6 + i] = { bb[i], bbF  + i * 256, 256 };
    }
    jobs.j[9]  = { Wh1, Wh1F, 2560 };
    jobs.j[10] = { bh1, bh1F, 10 };
    jobs.j[11] = { Wh2, Wh2F, 10 };
    jobs.j[12] = { bh2, bh2F, 1 };
    decode_many<<<dim3(13), dim3(256), 0, stream>>>(jobs, flags);

    dim3 gemm_grid((N + 127) / 128, 4);
    for (int L = 0; L < 3; L++){
        const void* A = (L == 0) ? feat : (const void*)QHi;
        int aRaw = (L == 0) ? 1 : 0;
        gemm_tpl<1><<<gemm_grid, dim3(256), 0, stream>>>(A, QLo, aRaw, BtH[L], BtL[L],
                                                         PR, N, Kin[L], flags, &flags[8 + L]);
        gemm_tpl<0><<<gemm_grid, dim3(256), 0, stream>>>(A, QLo, aRaw, BtH[L], BtL[L],
                                                         PR, N, Kin[L], flags, &flags[8 + L]);
        fused_agg<<<dim3((N + 3) / 4), dim3(256), 0, stream>>>(PR, srcS, eaS, off,
                                                               WeF + L * 256, attF + L * 256,
                                                               bbF + L * 256, QHi, QLo, N);
    }
    col_max2<<<dim3(256), dim3(256), 0, stream>>>(QHi, QLo, pool, N);
    head_kernel<<<dim3(1), dim3(64), 0, stream>>>(pool, Wh1F, bh1F, Wh2F, bh2F, d_out, flags);
    (void)n_in; (void)out_size;
}

// Round 6
// 858.171 us; speedup vs baseline: 1.4780x; 1.0039x over previous
//
#include <hip/hip_runtime.h>
#include <cstddef>
#include <cstdint>

typedef __attribute__((ext_vector_type(8))) short short8v;
typedef __attribute__((ext_vector_type(4))) short short4v;
typedef __attribute__((ext_vector_type(4))) float floatx4;

__device__ __forceinline__ float b2f(short u){
    return __uint_as_float(((unsigned)(unsigned short)u) << 16);
}
__device__ __forceinline__ short f2b(float f){
    unsigned x = __float_as_uint(f);
    unsigned r = x + 0x7FFFu + ((x >> 16) & 1u);
    return (short)(r >> 16);
}
__device__ __forceinline__ float loadF(const void* p, size_t i, int isBf16){
    return isBf16 ? b2f(((const short*)p)[i]) : ((const float*)p)[i];
}
__device__ __forceinline__ int loadI(const void* p, size_t i, int isI64){
    return isI64 ? ((const int*)p)[2 * i] : ((const int*)p)[i];
}
// async global->LDS, 16B per lane; dest = lds_base + lane*16 (wave-uniform base)
__device__ __forceinline__ void gload16(const void* g, void* l){
    __builtin_amdgcn_global_load_lds(
        (const __attribute__((address_space(1))) void*)g,
        (__attribute__((address_space(3))) void*)l, 16, 0, 0);
}

// flags: [0]=floats-bf16 [1]=ints-i64 [8..10]=B-hasLo per layer
__global__ void detect_kernel(const void* feat, const void* ei, int E, int* flags){
    int lane = threadIdx.x;
    if (lane >= 8 && lane < 16) flags[lane] = 0;
    const unsigned short* fs = (const unsigned short*)feat;
    int plaus = 0;
    for (int j = lane; j < 128; j += 64){
        unsigned short s = fs[2 * j];
        int e = (s >> 7) & 0xFF;
        if (s == 0 || (e >= 100 && e <= 140)) plaus++;
    }
    #pragma unroll
    for (int o = 32; o > 0; o >>= 1) plaus += __shfl_xor(plaus, o);
    const int* ew = (const int*)ei;
    int zeros = 0;
    for (int j = lane; j < 128; j += 64) if (ew[2 * j + 1] == 0) zeros++;
    #pragma unroll
    for (int o = 32; o > 0; o >>= 1) zeros += __shfl_xor(zeros, o);
    if (lane == 0){ flags[0] = (plaus >= 64) ? 1 : 0; flags[1] = (zeros >= 64) ? 1 : 0; }
    (void)E;
}

__global__ void sentinel_kernel(void* out, const int* flags, float v){
    if (threadIdx.x == 0){
        if (flags[0]) ((short*)out)[0] = f2b(v);
        else          ((float*)out)[0] = v;
    }
}

// ---------------- preprocessing: CSR by dst ----------------
__global__ void zero3(int* cnt, int* fill, unsigned* pool, int N){
    int i = blockIdx.x * 256 + threadIdx.x;
    if (i < N){ cnt[i] = 0; fill[i] = 0; }
    if (i < 256) pool[i] = 0u;
}

__global__ void hist_kernel(const void* __restrict__ ei, int* __restrict__ cnt, int E,
                            const int* __restrict__ flags){
    int i = blockIdx.x * 256 + threadIdx.x;
    if (i < E) atomicAdd(&cnt[loadI(ei, (size_t)E + i, flags[1])], 1);
}

// ---- 3-phase scan ----
__global__ void scanA(const int* __restrict__ cnt, int* __restrict__ off,
                      int* __restrict__ partial, int N){
    __shared__ int wsum[16];
    const int t = threadIdx.x, w = t >> 6, lane = t & 63;
    int i = blockIdx.x * 1024 + t;
    int v = (i < N) ? cnt[i] : 0;
    int x = v;
    #pragma unroll
    for (int o = 1; o < 64; o <<= 1){
        int y = __shfl_up(x, o);
        if (lane >= o) x += y;
    }
    if (lane == 63) wsum[w] = x;
    __syncthreads();
    if (w == 0){
        int mv = (lane < 16) ? wsum[lane] : 0;
        int xx = mv;
        #pragma unroll
        for (int o = 1; o < 16; o <<= 1){
            int y = __shfl_up(xx, o);
            if (lane >= o) xx += y;
        }
        if (lane < 16) wsum[lane] = xx - mv;
    }
    __syncthreads();
    int incl = x + wsum[w];
    if (i < N) off[i] = incl - v;
    if (t == 1023) partial[blockIdx.x] = incl;
}

__global__ void scanB(int* __restrict__ partial, int* __restrict__ off, int nb, int N){
    int lane = threadIdx.x;
    int v = (lane < nb) ? partial[lane] : 0;
    int x = v;
    #pragma unroll
    for (int o = 1; o < 64; o <<= 1){
        int y = __shfl_up(x, o);
        if (lane >= o) x += y;
    }
    if (lane < nb) partial[lane] = x - v;
    if (lane == 63) off[N] = x;
}

__global__ void scanC(int* __restrict__ off, const int* __restrict__ partial, int N){
    int i = blockIdx.x * 1024 + threadIdx.x;
    if (i < N) off[i] += partial[blockIdx.x];
}

// scatter edges into CSR; pack {src, edge_attr} as int2
__global__ void scatter_kernel(const void* __restrict__ ei, const void* __restrict__ ea,
                               const int* __restrict__ off, int* __restrict__ fill,
                               int2* __restrict__ se, int E, const int* __restrict__ flags){
    int i = blockIdx.x * 256 + threadIdx.x;
    if (i >= E) return;
    int d = loadI(ei, (size_t)E + i, flags[1]);
    int pos = off[d] + atomicAdd(&fill[d], 1);
    int2 q;
    q.x = loadI(ei, (size_t)i, flags[1]);
    q.y = __float_as_int(loadF(ea, (size_t)i, flags[0]));
    se[pos] = q;
}

// W [K x 256] -> Bt hi/lo [... x K] (concat offset applied by caller)
__global__ void prep_b(const void* __restrict__ W, short* __restrict__ bhi,
                       short* __restrict__ blo, int K, const int* __restrict__ flags,
                       int* __restrict__ hasLo){
    int idx = blockIdx.x * 256 + threadIdx.x;   // grid = K blocks
    int k = idx >> 8, c = idx & 255;
    float v = loadF(W, idx, flags[0]);
    short h = f2b(v);
    short l = f2b(v - b2f(h));
    bhi[(size_t)c * K + k] = h;
    blo[(size_t)c * K + k] = l;
    if (__ballot(l != 0) != 0ull && (threadIdx.x & 63) == 0) atomicOr(hasLo, 1);
}

// fused small-array decode: 13 jobs in one launch
struct DJob { const void* src; float* dst; int n; };
struct DJobs { DJob j[13]; };
__global__ void decode_many(DJobs jobs, const int* __restrict__ flags){
    const DJob J = jobs.j[blockIdx.x];
    int fbf = flags[0];
    for (int i = threadIdx.x; i < J.n; i += 256)
        J.dst[i] = loadF(J.src, (size_t)i, fbf);
}

// -------- fused-pair split GEMM: C[M x 512] = A[M x K] * Bt[512 x K]^T --------
// global_load_lds staging with pre-swizzled SOURCE (linear LDS dest) + swizzled read.
// BZ=1: bf16 weights (B-lo == 0), 48KB LDS -> 3 blocks/CU. BZ=0: f32-weight insurance.
template<int BZ>
__global__ __launch_bounds__(256, 3) void gemm_tpl(
        const void* __restrict__ A, const short* __restrict__ Alo, int aRaw,
        const short* __restrict__ Bhi, const short* __restrict__ Blo,
        float* __restrict__ C, int M, int K,
        const int* __restrict__ flags, const int* __restrict__ bLoFlag){
    if (BZ ? (bLoFlag[0] != 0) : (bLoFlag[0] == 0)) return;
    __shared__ __align__(16) short Ah[128 * 64];
    __shared__ __align__(16) short Al[128 * 64];
    __shared__ __align__(16) short Bh[128 * 64];
    __shared__ __align__(16) short Bl[BZ ? 8 : 128 * 64];
    const int fbf = flags[0];
    const int az = (aRaw && fbf) ? 1 : 0;     // A-lo structurally zero (raw bf16 A)
    const int aF32 = (aRaw && !fbf) ? 1 : 0;  // raw f32 A: register-stage + split
    const int t = threadIdx.x;
    const int w = t >> 6, lane = t & 63;
    const int wr = w >> 1, wc = w & 1;
    const int bRow = blockIdx.x * 128;
    const int bCol = blockIdx.y * 128;
    const short* Ahp = (const short*)A;

    floatx4 acc[4][4];
    #pragma unroll
    for (int m = 0; m < 4; m++)
        #pragma unroll
        for (int n = 0; n < 4; n++) acc[m][n] = (floatx4){0.f, 0.f, 0.f, 0.f};

    for (int k0 = 0; k0 < K; k0 += 64){
        // ---- stage via global_load_lds: LDS slot s of row r holds global chunk s^(r&7)
        // so we fetch chunk cl^(r&7) into linear slot cl (inverse == forward, XOR involution)
        #pragma unroll
        for (int ps = 0; ps < 4; ps++){
            int seg = ps * 4 + w;              // 16 segs x 8 rows
            int row = seg * 8 + (lane >> 3);
            int cl  = lane & 7;
            int cg  = cl ^ (row & 7);
            int gr = bRow + row; if (gr >= M) gr = M - 1;
            size_t ga = (size_t)gr * K + k0 + cg * 8;
            if (!aF32){
                gload16(&Ahp[ga], &Ah[seg * 512]);
                if (!az) gload16(&Alo[ga], &Al[seg * 512]);
            }
            size_t gb = (size_t)(bCol + row) * K + k0 + cg * 8;
            gload16(&Bhi[gb], &Bh[seg * 512]);
            if (!BZ) gload16(&Blo[gb], &Bl[seg * 512]);
        }
        if (aF32){
            // f32 A fallback: register stage, split, swizzled ds_write
            #pragma unroll
            for (int i = 0; i < 4; i++){
                int e = i * 256 + t;
                int r = e >> 3, c = e & 7;
                int sw = ((c ^ (r & 7)) << 3);
                int gr = bRow + r; if (gr >= M) gr = M - 1;
                size_t ga = (size_t)gr * K + k0 + c * 8;
                const float* Af = (const float*)A;
                floatx4 v0 = *(const floatx4*)&Af[ga];
                floatx4 v1 = *(const floatx4*)&Af[ga + 4];
                short8v h, l;
                #pragma unroll
                for (int j = 0; j < 4; j++){
                    short hj = f2b(v0[j]);
                    h[j] = hj; l[j] = f2b(v0[j] - b2f(hj));
                    short hk = f2b(v1[j]);
                    h[4 + j] = hk; l[4 + j] = f2b(v1[j] - b2f(hk));
                }
                *(short8v*)&Ah[r * 64 + sw] = h;
                *(short8v*)&Al[r * 64 + sw] = l;
            }
        }
        __syncthreads();
        #pragma unroll
        for (int ks = 0; ks < 2; ks++){
            short8v a_h[4], a_l[4], b_h[4], b_l[4];
            #pragma unroll
            for (int m = 0; m < 4; m++){
                int ar = wr * 64 + m * 16 + (lane & 15);
                int co = (((ks * 64 + ((lane >> 4) << 4)) ^ ((ar & 7) << 4)) >> 1);
                a_h[m] = *(const short8v*)&Ah[ar * 64 + co];
                if (!az) a_l[m] = *(const short8v*)&Al[ar * 64 + co];
            }
            #pragma unroll
            for (int n = 0; n < 4; n++){
                int br = wc * 64 + n * 16 + (lane & 15);
                int co = (((ks * 64 + ((lane >> 4) << 4)) ^ ((br & 7) << 4)) >> 1);
                b_h[n] = *(const short8v*)&Bh[br * 64 + co];
                if (!BZ) b_l[n] = *(const short8v*)&Bl[br * 64 + co];
            }
            #pragma unroll
            for (int m = 0; m < 4; m++)
                #pragma unroll
                for (int n = 0; n < 4; n++){
                    if (!az) acc[m][n] = __builtin_amdgcn_mfma_f32_16x16x32_bf16(
                                             a_l[m], b_h[n], acc[m][n], 0, 0, 0);
                    if (!BZ) acc[m][n] = __builtin_amdgcn_mfma_f32_16x16x32_bf16(
                                             a_h[m], b_l[n], acc[m][n], 0, 0, 0);
                    acc[m][n] = __builtin_amdgcn_mfma_f32_16x16x32_bf16(
                                    a_h[m], b_h[n], acc[m][n], 0, 0, 0);
                }
        }
        __syncthreads();
    }
    #pragma unroll
    for (int m = 0; m < 4; m++){
        int rb = bRow + wr * 64 + m * 16 + ((lane >> 4) << 2);
        #pragma unroll
        for (int n = 0; n < 4; n++){
            int cg = bCol + wc * 64 + n * 16 + (lane & 15);
            #pragma unroll
            for (int r = 0; r < 4; r++){
                int gr = rb + r;
                if (gr < M) C[(size_t)gr * 512 + cg] = acc[m][n][r];
            }
        }
    }
}

// ------- fused per-node: scores + online softmax + aggregation + bias + relu -------
__global__ __launch_bounds__(256) void fused_agg(const float* __restrict__ PR,
        const int2* __restrict__ se, const int* __restrict__ off,
        const float* __restrict__ WeF, const float* __restrict__ attF,
        const float* __restrict__ bbF,
        short* __restrict__ QHi, short* __restrict__ QLo, int N){
    int node = blockIdx.x * 4 + (threadIdx.x >> 6);
    int lane = threadIdx.x & 63;
    if (node >= N) return;
    const int beg = off[node], end = off[node + 1];
    const int dd = lane << 2;
    const floatx4 xr4 = *(const floatx4*)&PR[(size_t)node * 512 + 256 + dd];
    const floatx4 we4 = *(const floatx4*)&WeF[dd];
    const floatx4 at4 = *(const floatx4*)&attF[dd];
    float m = -1e30f, ssum = 0.f;
    floatx4 a4 = (floatx4){0.f, 0.f, 0.f, 0.f};
    for (int k0 = beg; k0 < end; k0 += 8){
        floatx4 v[8]; float pp[8]; float eav[8];
        #pragma unroll
        for (int c = 0; c < 8; c++){
            int k = k0 + c; if (k >= end) k = end - 1;
            int2 q = se[k];
            eav[c] = __int_as_float(q.y);
            v[c] = *(const floatx4*)&PR[(size_t)q.x * 512 + dd];
        }
        #pragma unroll
        for (int c = 0; c < 8; c++){
            float p = 0.f;
            #pragma unroll
            for (int j = 0; j < 4; j++){
                float tv = v[c][j] + xr4[j] + eav[c] * we4[j];
                tv = tv > 0.f ? tv : 0.2f * tv;
                p += tv * at4[j];
            }
            #pragma unroll
            for (int o = 32; o > 0; o >>= 1) p += __shfl_xor(p, o);
            pp[c] = (k0 + c < end) ? p : -1e30f;
        }
        float pm = pp[0];
        #pragma unroll
        for (int c = 1; c < 8; c++) pm = fmaxf(pm, pp[c]);
        if (pm > m){                      // wave-uniform: rescale only when max grows
            float newm = pm;
            float scale = __expf(m - newm);
            ssum *= scale;
            a4[0] *= scale; a4[1] *= scale; a4[2] *= scale; a4[3] *= scale;
            m = newm;
        }
        #pragma unroll
        for (int c = 0; c < 8; c++){
            float wgt = __expf(pp[c] - m);
            ssum += wgt;
            a4[0] += wgt * v[c][0]; a4[1] += wgt * v[c][1];
            a4[2] += wgt * v[c][2]; a4[3] += wgt * v[c][3];
        }
    }
    float inv = (end > beg) ? 1.f / ssum : 0.f;
    short4v h4, l4;
    #pragma unroll
    for (int j = 0; j < 4; j++){
        float o = fmaxf(a4[j] * inv + bbF[dd + j], 0.f);
        short h = f2b(o);
        h4[j] = h;
        l4[j] = f2b(o - b2f(h));
    }
    *(short4v*)&QHi[(size_t)node * 256 + dd] = h4;
    *(short4v*)&QLo[(size_t)node * 256 + dd] = l4;
}

// ---------------- global max pool over hi/lo activation ----------------
__global__ __launch_bounds__(256) void col_max2(const short* __restrict__ hi,
        const short* __restrict__ lo, unsigned* __restrict__ pool, int N){
    int lane = threadIdx.x & 63;
    int w = threadIdx.x >> 6;
    int dd = lane << 2;
    floatx4 mx = (floatx4){0.f, 0.f, 0.f, 0.f};
    for (int r = blockIdx.x * 4 + w; r < N; r += gridDim.x * 4){
        short4v h = *(const short4v*)&hi[(size_t)r * 256 + dd];
        short4v l = *(const short4v*)&lo[(size_t)r * 256 + dd];
        mx[0] = fmaxf(mx[0], b2f(h[0]) + b2f(l[0]));
        mx[1] = fmaxf(mx[1], b2f(h[1]) + b2f(l[1]));
        mx[2] = fmaxf(mx[2], b2f(h[2]) + b2f(l[2]));
        mx[3] = fmaxf(mx[3], b2f(h[3]) + b2f(l[3]));
    }
    atomicMax(&pool[dd + 0], __float_as_uint(mx[0]));
    atomicMax(&pool[dd + 1], __float_as_uint(mx[1]));
    atomicMax(&pool[dd + 2], __float_as_uint(mx[2]));
    atomicMax(&pool[dd + 3], __float_as_uint(mx[3]));
}

__global__ void head_kernel(const unsigned* __restrict__ pool, const float* __restrict__ Wh1F,
        const float* __restrict__ bh1F, const float* __restrict__ Wh2F,
        const float* __restrict__ bh2F, void* __restrict__ out, const int* __restrict__ flags){
    int lane = threadIdx.x;
    float acc = 0.f;
    if (lane < 10){
        acc = bh1F[lane];
        for (int d = 0; d < 256; ++d)
            acc += __uint_as_float(pool[d]) * Wh1F[d * 10 + lane];
        acc = fmaxf(acc, 0.f) * Wh2F[lane];
    }
    #pragma unroll
    for (int o = 32; o > 0; o >>= 1) acc += __shfl_xor(acc, o);
    if (lane == 0){
        float r = acc + bh2F[0];
        if (flags[0]) ((short*)out)[0] = f2b(r);
        else          ((float*)out)[0] = r;
    }
}

extern "C" void kernel_launch(void* const* d_in, const int* in_sizes, int n_in,
                              void* d_out, int out_size, void* d_ws, size_t ws_size,
                              hipStream_t stream){
    const void* feat = d_in[0];
    const void* ei   = d_in[1];
    const void* ea   = d_in[2];
    const void* Wl[3] = {d_in[3], d_in[8],  d_in[13]};
    const void* Wr[3] = {d_in[4], d_in[9],  d_in[14]};
    const void* We[3] = {d_in[5], d_in[10], d_in[15]};
    const void* at[3] = {d_in[6], d_in[11], d_in[16]};
    const void* bb[3] = {d_in[7], d_in[12], d_in[17]};
    const void* Wh1 = d_in[18];
    const void* bh1 = d_in[19];
    const void* Wh2 = d_in[20];
    const void* bh2 = d_in[21];

    const int N = in_sizes[0] / 128;
    const int E = in_sizes[1] / 2;
    const int Kin[3] = {128, 256, 256};
    const int nb = (N + 1023) / 1024;

    char* p = (char*)d_ws;
    auto alloc = [&](size_t bytes) -> void* {
        void* r = (void*)p; p += (bytes + 255) & ~(size_t)255; return r;
    };
    int*   flags   = (int*)alloc(256);
    int*   partial = (int*)alloc(256 * 4);
    int*   off   = (int*)alloc((size_t)(N + 1) * 4);
    int*   cnt   = (int*)alloc((size_t)N * 4);
    int*   fill  = (int*)alloc((size_t)N * 4);
    int2*  se    = (int2*)alloc((size_t)E * 8);
    float* PR    = (float*)alloc((size_t)N * 512 * 4);
    short* QHi   = (short*)alloc((size_t)N * 256 * 2);
    short* QLo   = (short*)alloc((size_t)N * 256 * 2);
    short* BtH[3]; short* BtL[3];
    for (int i = 0; i < 3; i++){
        BtH[i] = (short*)alloc((size_t)512 * Kin[i] * 2);
        BtL[i] = (short*)alloc((size_t)512 * Kin[i] * 2);
    }
    float* WeF  = (float*)alloc(3 * 256 * 4);
    float* attF = (float*)alloc(3 * 256 * 4);
    float* bbF  = (float*)alloc(3 * 256 * 4);
    float* Wh1F = (float*)alloc(2560 * 4);
    float* bh1F = (float*)alloc(16 * 4);
    float* Wh2F = (float*)alloc(16 * 4);
    float* bh2F = (float*)alloc(4 * 4);
    unsigned* pool = (unsigned*)alloc(256 * 4);
    size_t need = (size_t)(p - (char*)d_ws);

    detect_kernel<<<dim3(1), dim3(64), 0, stream>>>(feat, ei, E, flags);
    sentinel_kernel<<<dim3(1), dim3(1), 0, stream>>>(d_out, flags, 777.0f);
    if (need > ws_size){
        sentinel_kernel<<<dim3(1), dim3(1), 0, stream>>>(d_out, flags, 555.0f);
        return;
    }

    zero3<<<dim3((N + 255) / 256), dim3(256), 0, stream>>>(cnt, fill, pool, N);
    hist_kernel<<<dim3((E + 255) / 256), dim3(256), 0, stream>>>(ei, cnt, E, flags);
    scanA<<<dim3(nb), dim3(1024), 0, stream>>>(cnt, off, partial, N);
    scanB<<<dim3(1), dim3(64), 0, stream>>>(partial, off, nb, N);
    scanC<<<dim3(nb), dim3(1024), 0, stream>>>(off, partial, N);
    scatter_kernel<<<dim3((E + 255) / 256), dim3(256), 0, stream>>>(ei, ea, off, fill,
                                                                    se, E, flags);
    for (int i = 0; i < 3; i++){
        prep_b<<<dim3(Kin[i]), dim3(256), 0, stream>>>(Wl[i], BtH[i], BtL[i],
                                                       Kin[i], flags, &flags[8 + i]);
        prep_b<<<dim3(Kin[i]), dim3(256), 0, stream>>>(Wr[i], BtH[i] + (size_t)256 * Kin[i],
                                                       BtL[i] + (size_t)256 * Kin[i],
                                                       Kin[i], flags, &flags[8 + i]);
    }
    DJobs jobs;
    for (int i = 0; i < 3; i++){
        jobs.j[i]     = { We[i], WeF  + i * 256, 256 };
        jobs.j[3 + i] = { at[i], attF + i * 256, 256 };
        jobs.j[6 + i] = { bb[i], bbF  + i * 256, 256 };
    }
    jobs.j[9]  = { Wh1, Wh1F, 2560 };
    jobs.j[10] = { bh1, bh1F, 10 };
    jobs.j[11] = { Wh2, Wh2F, 10 };
    jobs.j[12] = { bh2, bh2F, 1 };
    decode_many<<<dim3(13), dim3(256), 0, stream>>>(jobs, flags);

    dim3 gemm_grid((N + 127) / 128, 4);
    for (int L = 0; L < 3; L++){
        const void* A = (L == 0) ? feat : (const void*)QHi;
        int aRaw = (L == 0) ? 1 : 0;
        gemm_tpl<1><<<gemm_grid, dim3(256), 0, stream>>>(A, QLo, aRaw, BtH[L], BtL[L],
                                                         PR, N, Kin[L], flags, &flags[8 + L]);
        gemm_tpl<0><<<gemm_grid, dim3(256), 0, stream>>>(A, QLo, aRaw, BtH[L], BtL[L],
                                                         PR, N, Kin[L], flags, &flags[8 + L]);
        fused_agg<<<dim3((N + 3) / 4), dim3(256), 0, stream>>>(PR, se, off,
                                                               WeF + L * 256, attF + L * 256,
                                                               bbF + L * 256, QHi, QLo, N);
    }
    col_max2<<<dim3(256), dim3(256), 0, stream>>>(QHi, QLo, pool, N);
    head_kernel<<<dim3(1), dim3(64), 0, stream>>>(pool, Wh1F, bh1F, Wh2F, bh2F, d_out, flags);
    (void)n_in; (void)out_size;
}

// Round 7
// 826.177 us; speedup vs baseline: 1.5353x; 1.0387x over previous
//
#include <hip/hip_runtime.h>
#include <cstddef>
#include <cstdint>

typedef __attribute__((ext_vector_type(8))) short short8v;
typedef __attribute__((ext_vector_type(4))) short short4v;
typedef __attribute__((ext_vector_type(4))) float floatx4;

__device__ __forceinline__ float b2f(short u){
    return __uint_as_float(((unsigned)(unsigned short)u) << 16);
}
__device__ __forceinline__ short f2b(float f){
    unsigned x = __float_as_uint(f);
    unsigned r = x + 0x7FFFu + ((x >> 16) & 1u);
    return (short)(r >> 16);
}
__device__ __forceinline__ float loadF(const void* p, size_t i, int isBf16){
    return isBf16 ? b2f(((const short*)p)[i]) : ((const float*)p)[i];
}
__device__ __forceinline__ int loadI(const void* p, size_t i, int isI64){
    return isI64 ? ((const int*)p)[2 * i] : ((const int*)p)[i];
}
// async global->LDS, 16B per lane; dest = lds_base + lane*16 (wave-uniform base)
__device__ __forceinline__ void gload16(const void* g, void* l){
    __builtin_amdgcn_global_load_lds(
        (const __attribute__((address_space(1))) void*)g,
        (__attribute__((address_space(3))) void*)l, 16, 0, 0);
}

// flags: [0]=floats-bf16 [1]=ints-i64 [8..10]=B-hasLo per layer
__global__ void detect_kernel(const void* feat, const void* ei, int E, int* flags){
    int lane = threadIdx.x;
    if (lane >= 8 && lane < 16) flags[lane] = 0;
    const unsigned short* fs = (const unsigned short*)feat;
    int plaus = 0;
    for (int j = lane; j < 128; j += 64){
        unsigned short s = fs[2 * j];
        int e = (s >> 7) & 0xFF;
        if (s == 0 || (e >= 100 && e <= 140)) plaus++;
    }
    #pragma unroll
    for (int o = 32; o > 0; o >>= 1) plaus += __shfl_xor(plaus, o);
    const int* ew = (const int*)ei;
    int zeros = 0;
    for (int j = lane; j < 128; j += 64) if (ew[2 * j + 1] == 0) zeros++;
    #pragma unroll
    for (int o = 32; o > 0; o >>= 1) zeros += __shfl_xor(zeros, o);
    if (lane == 0){ flags[0] = (plaus >= 64) ? 1 : 0; flags[1] = (zeros >= 64) ? 1 : 0; }
    (void)E;
}

__global__ void sentinel_kernel(void* out, const int* flags, float v){
    if (threadIdx.x == 0){
        if (flags[0]) ((short*)out)[0] = f2b(v);
        else          ((float*)out)[0] = v;
    }
}

// ---------------- preprocessing: CSR by dst ----------------
__global__ void zero3(int* cnt, int* fill, unsigned* pool, int N){
    int i = blockIdx.x * 256 + threadIdx.x;
    if (i < N){ cnt[i] = 0; fill[i] = 0; }
    if (i < 256) pool[i] = 0u;
}

__global__ void hist_kernel(const void* __restrict__ ei, int* __restrict__ cnt, int E,
                            const int* __restrict__ flags){
    int i = blockIdx.x * 256 + threadIdx.x;
    if (i < E) atomicAdd(&cnt[loadI(ei, (size_t)E + i, flags[1])], 1);
}

// ---- 3-phase scan ----
__global__ void scanA(const int* __restrict__ cnt, int* __restrict__ off,
                      int* __restrict__ partial, int N){
    __shared__ int wsum[16];
    const int t = threadIdx.x, w = t >> 6, lane = t & 63;
    int i = blockIdx.x * 1024 + t;
    int v = (i < N) ? cnt[i] : 0;
    int x = v;
    #pragma unroll
    for (int o = 1; o < 64; o <<= 1){
        int y = __shfl_up(x, o);
        if (lane >= o) x += y;
    }
    if (lane == 63) wsum[w] = x;
    __syncthreads();
    if (w == 0){
        int mv = (lane < 16) ? wsum[lane] : 0;
        int xx = mv;
        #pragma unroll
        for (int o = 1; o < 16; o <<= 1){
            int y = __shfl_up(xx, o);
            if (lane >= o) xx += y;
        }
        if (lane < 16) wsum[lane] = xx - mv;
    }
    __syncthreads();
    int incl = x + wsum[w];
    if (i < N) off[i] = incl - v;
    if (t == 1023) partial[blockIdx.x] = incl;
}

__global__ void scanB(int* __restrict__ partial, int* __restrict__ off, int nb, int N){
    int lane = threadIdx.x;
    int v = (lane < nb) ? partial[lane] : 0;
    int x = v;
    #pragma unroll
    for (int o = 1; o < 64; o <<= 1){
        int y = __shfl_up(x, o);
        if (lane >= o) x += y;
    }
    if (lane < nb) partial[lane] = x - v;
    if (lane == 63) off[N] = x;
}

__global__ void scanC(int* __restrict__ off, const int* __restrict__ partial, int N){
    int i = blockIdx.x * 1024 + threadIdx.x;
    if (i < N) off[i] += partial[blockIdx.x];
}

// scatter edges into CSR (round-5 form: separate srcS / eaS)
__global__ void scatter_kernel(const void* __restrict__ ei, const void* __restrict__ ea,
                               const int* __restrict__ off, int* __restrict__ fill,
                               int* __restrict__ srcS, float* __restrict__ eaS,
                               int E, const int* __restrict__ flags){
    int i = blockIdx.x * 256 + threadIdx.x;
    if (i >= E) return;
    int d = loadI(ei, (size_t)E + i, flags[1]);
    int pos = off[d] + atomicAdd(&fill[d], 1);
    srcS[pos] = loadI(ei, (size_t)i, flags[1]);
    eaS[pos] = loadF(ea, (size_t)i, flags[0]);
}

// W [K x 256] -> Bt hi/lo [... x K] (concat offset applied by caller)
__global__ void prep_b(const void* __restrict__ W, short* __restrict__ bhi,
                       short* __restrict__ blo, int K, const int* __restrict__ flags,
                       int* __restrict__ hasLo){
    int idx = blockIdx.x * 256 + threadIdx.x;   // grid = K blocks
    int k = idx >> 8, c = idx & 255;
    float v = loadF(W, idx, flags[0]);
    short h = f2b(v);
    short l = f2b(v - b2f(h));
    bhi[(size_t)c * K + k] = h;
    blo[(size_t)c * K + k] = l;
    if (__ballot(l != 0) != 0ull && (threadIdx.x & 63) == 0) atomicOr(hasLo, 1);
}

// fused small-array decode: 13 jobs in one launch
struct DJob { const void* src; float* dst; int n; };
struct DJobs { DJob j[13]; };
__global__ void decode_many(DJobs jobs, const int* __restrict__ flags){
    const DJob J = jobs.j[blockIdx.x];
    int fbf = flags[0];
    for (int i = threadIdx.x; i < J.n; i += 256)
        J.dst[i] = loadF(J.src, (size_t)i, fbf);
}

// -------- fused-pair split GEMM: C[M x 512] = A[M x K] * Bt[512 x K]^T --------
// BK=32 double-buffered global_load_lds pipeline with counted vmcnt (T3-min):
// iter t: STAGE(t+1, buf^1) -> vmcnt(S) [drains tile-t loads only] -> barrier ->
//         ds_read+MFMA from buf -> barrier -> swap.
// Swizzle (involution, both sides): source chunk = cl ^ (row&3); read co = (g ^ (row&3)).
template<int BZ>
__global__ __launch_bounds__(256, 3) void gemm_tpl(
        const void* __restrict__ A, const short* __restrict__ Alo, int aRaw,
        const short* __restrict__ Bhi, const short* __restrict__ Blo,
        float* __restrict__ C, int M, int K,
        const int* __restrict__ flags, const int* __restrict__ bLoFlag){
    if (BZ ? (bLoFlag[0] != 0) : (bLoFlag[0] == 0)) return;
    __shared__ __align__(16) short Ah[2][128 * 32];
    __shared__ __align__(16) short Al[2][128 * 32];
    __shared__ __align__(16) short Bh[2][128 * 32];
    __shared__ __align__(16) short Bl[2][BZ ? 8 : 128 * 32];
    const int fbf = flags[0];
    const int az   = (aRaw && fbf) ? 1 : 0;   // A-lo structurally zero (raw bf16 A)
    const int aF32 = (aRaw && !fbf) ? 1 : 0;  // raw f32 A: register-stage + split
    const int t = threadIdx.x;
    const int w = t >> 6, lane = t & 63;
    const int wr = w >> 1, wc = w & 1;
    const int bRow = blockIdx.x * 128;
    const int bCol = blockIdx.y * 128;
    const short* Ahp = (const short*)A;
    const float* Af  = (const float*)A;

    floatx4 acc[4][4];
    #pragma unroll
    for (int m = 0; m < 4; m++)
        #pragma unroll
        for (int n = 0; n < 4; n++) acc[m][n] = (floatx4){0.f, 0.f, 0.f, 0.f};

    // stage one 128x32 K-tile (8KB/buffer); 2 chunks of 16B per thread per buffer
    auto STAGE = [&](int buf, int kk){
        #pragma unroll
        for (int iss = 0; iss < 2; iss++){
            int ci  = (iss * 4 + w) * 64 + lane;      // chunk index 0..511
            int row = ci >> 2;
            int cg  = (ci & 3) ^ (row & 3);           // pre-swizzled source chunk
            int gr = bRow + row; if (gr >= M) gr = M - 1;
            size_t ga  = (size_t)gr * K + kk + cg * 8;
            size_t gbi = (size_t)(bCol + row) * K + kk + cg * 8;
            int seg = (iss * 4 + w) * 512;            // linear LDS dest (shorts)
            if (!aF32){
                gload16(&Ahp[ga], &Ah[buf][seg]);
                if (!az) gload16(&Alo[ga], &Al[buf][seg]);
            }
            gload16(&Bhi[gbi], &Bh[buf][seg]);
            if (!BZ) gload16(&Blo[gbi], &Bl[buf][seg]);
        }
        if (aF32){   // insurance path: register-stage f32, split, swizzled ds_write
            #pragma unroll
            for (int iss = 0; iss < 2; iss++){
                int ci  = (iss * 4 + w) * 64 + lane;
                int row = ci >> 2, cl = ci & 3;
                int slot = cl ^ (row & 3);
                int gr = bRow + row; if (gr >= M) gr = M - 1;
                size_t ga = (size_t)gr * K + kk + cl * 8;
                floatx4 v0 = *(const floatx4*)&Af[ga];
                floatx4 v1 = *(const floatx4*)&Af[ga + 4];
                short8v h, l;
                #pragma unroll
                for (int j = 0; j < 4; j++){
                    short hj = f2b(v0[j]);
                    h[j] = hj; l[j] = f2b(v0[j] - b2f(hj));
                    short hk = f2b(v1[j]);
                    h[4 + j] = hk; l[4 + j] = f2b(v1[j] - b2f(hk));
                }
                *(short8v*)&Ah[buf][row * 32 + slot * 8] = h;
                *(short8v*)&Al[buf][row * 32 + slot * 8] = l;
            }
        }
    };

    const int T = K >> 5;
    STAGE(0, 0);
    int cur = 0;
    for (int kt = 0; kt < T; ++kt){
        if (kt + 1 < T) STAGE(cur ^ 1, (kt + 1) << 5);
        if (aF32){
            asm volatile("s_waitcnt vmcnt(0) lgkmcnt(0)" ::: "memory");
        } else if (kt + 1 >= T){
            asm volatile("s_waitcnt vmcnt(0)" ::: "memory");
        } else if (az){
            if (BZ) asm volatile("s_waitcnt vmcnt(4)" ::: "memory");
            else    asm volatile("s_waitcnt vmcnt(6)" ::: "memory");
        } else {
            if (BZ) asm volatile("s_waitcnt vmcnt(6)" ::: "memory");
            else    asm volatile("s_waitcnt vmcnt(8)" ::: "memory");
        }
        __builtin_amdgcn_s_barrier();
        short8v a_h[4], a_l[4], b_h[4], b_l[4];
        #pragma unroll
        for (int m = 0; m < 4; m++){
            int ar = wr * 64 + m * 16 + (lane & 15);
            int co = (((lane >> 4) ^ (ar & 3)) << 3);
            a_h[m] = *(const short8v*)&Ah[cur][ar * 32 + co];
            if (!az) a_l[m] = *(const short8v*)&Al[cur][ar * 32 + co];
        }
        #pragma unroll
        for (int n = 0; n < 4; n++){
            int br = wc * 64 + n * 16 + (lane & 15);
            int co = (((lane >> 4) ^ (br & 3)) << 3);
            b_h[n] = *(const short8v*)&Bh[cur][br * 32 + co];
            if (!BZ) b_l[n] = *(const short8v*)&Bl[cur][br * 32 + co];
        }
        #pragma unroll
        for (int m = 0; m < 4; m++)
            #pragma unroll
            for (int n = 0; n < 4; n++){
                if (!az) acc[m][n] = __builtin_amdgcn_mfma_f32_16x16x32_bf16(
                                         a_l[m], b_h[n], acc[m][n], 0, 0, 0);
                if (!BZ) acc[m][n] = __builtin_amdgcn_mfma_f32_16x16x32_bf16(
                                         a_h[m], b_l[n], acc[m][n], 0, 0, 0);
                acc[m][n] = __builtin_amdgcn_mfma_f32_16x16x32_bf16(
                                a_h[m], b_h[n], acc[m][n], 0, 0, 0);
            }
        __builtin_amdgcn_s_barrier();
        cur ^= 1;
    }
    #pragma unroll
    for (int m = 0; m < 4; m++){
        int rb = bRow + wr * 64 + m * 16 + ((lane >> 4) << 2);
        #pragma unroll
        for (int n = 0; n < 4; n++){
            int cg = bCol + wc * 64 + n * 16 + (lane & 15);
            #pragma unroll
            for (int r = 0; r < 4; r++){
                int gr = rb + r;
                if (gr < M) C[(size_t)gr * 512 + cg] = acc[m][n][r];
            }
        }
    }
}

// ------- fused per-node (round-5 form, 64 VGPR): scores + online softmax + agg -------
__global__ __launch_bounds__(256) void fused_agg(const float* __restrict__ PR,
        const int* __restrict__ srcS, const float* __restrict__ eaS,
        const int* __restrict__ off, const float* __restrict__ WeF,
        const float* __restrict__ attF, const float* __restrict__ bbF,
        short* __restrict__ QHi, short* __restrict__ QLo, int N){
    int node = blockIdx.x * 4 + (threadIdx.x >> 6);
    int lane = threadIdx.x & 63;
    if (node >= N) return;
    const int beg = off[node], end = off[node + 1];
    const int dd = lane << 2;
    const floatx4 xr4 = *(const floatx4*)&PR[(size_t)node * 512 + 256 + dd];
    const floatx4 we4 = *(const floatx4*)&WeF[dd];
    const floatx4 at4 = *(const floatx4*)&attF[dd];
    float m = -1e30f, ssum = 0.f;
    floatx4 a4 = (floatx4){0.f, 0.f, 0.f, 0.f};
    for (int k0 = beg; k0 < end; k0 += 8){
        floatx4 v[8]; float pp[8]; float eav[8];
        #pragma unroll
        for (int c = 0; c < 8; c++){
            int k = k0 + c; if (k >= end) k = end - 1;
            int s = srcS[k];
            eav[c] = eaS[k];
            v[c] = *(const floatx4*)&PR[(size_t)s * 512 + dd];
        }
        #pragma unroll
        for (int c = 0; c < 8; c++){
            float p = 0.f;
            #pragma unroll
            for (int j = 0; j < 4; j++){
                float tv = v[c][j] + xr4[j] + eav[c] * we4[j];
                tv = tv > 0.f ? tv : 0.2f * tv;
                p += tv * at4[j];
            }
            #pragma unroll
            for (int o = 32; o > 0; o >>= 1) p += __shfl_xor(p, o);
            pp[c] = (k0 + c < end) ? p : -1e30f;
        }
        float pm = pp[0];
        #pragma unroll
        for (int c = 1; c < 8; c++) pm = fmaxf(pm, pp[c]);
        float newm = fmaxf(m, pm);
        float scale = __expf(m - newm);
        ssum *= scale;
        a4[0] *= scale; a4[1] *= scale; a4[2] *= scale; a4[3] *= scale;
        #pragma unroll
        for (int c = 0; c < 8; c++){
            float wgt = __expf(pp[c] - newm);
            ssum += wgt;
            a4[0] += wgt * v[c][0]; a4[1] += wgt * v[c][1];
            a4[2] += wgt * v[c][2]; a4[3] += wgt * v[c][3];
        }
        m = newm;
    }
    float inv = (end > beg) ? 1.f / ssum : 0.f;
    short4v h4, l4;
    #pragma unroll
    for (int j = 0; j < 4; j++){
        float o = fmaxf(a4[j] * inv + bbF[dd + j], 0.f);
        short h = f2b(o);
        h4[j] = h;
        l4[j] = f2b(o - b2f(h));
    }
    *(short4v*)&QHi[(size_t)node * 256 + dd] = h4;
    *(short4v*)&QLo[(size_t)node * 256 + dd] = l4;
}

// ---------------- global max pool over hi/lo activation ----------------
__global__ __launch_bounds__(256) void col_max2(const short* __restrict__ hi,
        const short* __restrict__ lo, unsigned* __restrict__ pool, int N){
    int lane = threadIdx.x & 63;
    int w = threadIdx.x >> 6;
    int dd = lane << 2;
    floatx4 mx = (floatx4){0.f, 0.f, 0.f, 0.f};
    for (int r = blockIdx.x * 4 + w; r < N; r += gridDim.x * 4){
        short4v h = *(const short4v*)&hi[(size_t)r * 256 + dd];
        short4v l = *(const short4v*)&lo[(size_t)r * 256 + dd];
        mx[0] = fmaxf(mx[0], b2f(h[0]) + b2f(l[0]));
        mx[1] = fmaxf(mx[1], b2f(h[1]) + b2f(l[1]));
        mx[2] = fmaxf(mx[2], b2f(h[2]) + b2f(l[2]));
        mx[3] = fmaxf(mx[3], b2f(h[3]) + b2f(l[3]));
    }
    atomicMax(&pool[dd + 0], __float_as_uint(mx[0]));
    atomicMax(&pool[dd + 1], __float_as_uint(mx[1]));
    atomicMax(&pool[dd + 2], __float_as_uint(mx[2]));
    atomicMax(&pool[dd + 3], __float_as_uint(mx[3]));
}

__global__ void head_kernel(const unsigned* __restrict__ pool, const float* __restrict__ Wh1F,
        const float* __restrict__ bh1F, const float* __restrict__ Wh2F,
        const float* __restrict__ bh2F, void* __restrict__ out, const int* __restrict__ flags){
    int lane = threadIdx.x;
    float acc = 0.f;
    if (lane < 10){
        acc = bh1F[lane];
        for (int d = 0; d < 256; ++d)
            acc += __uint_as_float(pool[d]) * Wh1F[d * 10 + lane];
        acc = fmaxf(acc, 0.f) * Wh2F[lane];
    }
    #pragma unroll
    for (int o = 32; o > 0; o >>= 1) acc += __shfl_xor(acc, o);
    if (lane == 0){
        float r = acc + bh2F[0];
        if (flags[0]) ((short*)out)[0] = f2b(r);
        else          ((float*)out)[0] = r;
    }
}

extern "C" void kernel_launch(void* const* d_in, const int* in_sizes, int n_in,
                              void* d_out, int out_size, void* d_ws, size_t ws_size,
                              hipStream_t stream){
    const void* feat = d_in[0];
    const void* ei   = d_in[1];
    const void* ea   = d_in[2];
    const void* Wl[3] = {d_in[3], d_in[8],  d_in[13]};
    const void* Wr[3] = {d_in[4], d_in[9],  d_in[14]};
    const void* We[3] = {d_in[5], d_in[10], d_in[15]};
    const void* at[3] = {d_in[6], d_in[11], d_in[16]};
    const void* bb[3] = {d_in[7], d_in[12], d_in[17]};
    const void* Wh1 = d_in[18];
    const void* bh1 = d_in[19];
    const void* Wh2 = d_in[20];
    const void* bh2 = d_in[21];

    const int N = in_sizes[0] / 128;
    const int E = in_sizes[1] / 2;
    const int Kin[3] = {128, 256, 256};
    const int nb = (N + 1023) / 1024;

    char* p = (char*)d_ws;
    auto alloc = [&](size_t bytes) -> void* {
        void* r = (void*)p; p += (bytes + 255) & ~(size_t)255; return r;
    };
    int*   flags   = (int*)alloc(256);
    int*   partial = (int*)alloc(256 * 4);
    int*   off   = (int*)alloc((size_t)(N + 1) * 4);
    int*   cnt   = (int*)alloc((size_t)N * 4);
    int*   fill  = (int*)alloc((size_t)N * 4);
    int*   srcS  = (int*)alloc((size_t)E * 4);
    float* eaS   = (float*)alloc((size_t)E * 4);
    float* PR    = (float*)alloc((size_t)N * 512 * 4);
    short* QHi   = (short*)alloc((size_t)N * 256 * 2);
    short* QLo   = (short*)alloc((size_t)N * 256 * 2);
    short* BtH[3]; short* BtL[3];
    for (int i = 0; i < 3; i++){
        BtH[i] = (short*)alloc((size_t)512 * Kin[i] * 2);
        BtL[i] = (short*)alloc((size_t)512 * Kin[i] * 2);
    }
    float* WeF  = (float*)alloc(3 * 256 * 4);
    float* attF = (float*)alloc(3 * 256 * 4);
    float* bbF  = (float*)alloc(3 * 256 * 4);
    float* Wh1F = (float*)alloc(2560 * 4);
    float* bh1F = (float*)alloc(16 * 4);
    float* Wh2F = (float*)alloc(16 * 4);
    float* bh2F = (float*)alloc(4 * 4);
    unsigned* pool = (unsigned*)alloc(256 * 4);
    size_t need = (size_t)(p - (char*)d_ws);

    detect_kernel<<<dim3(1), dim3(64), 0, stream>>>(feat, ei, E, flags);
    sentinel_kernel<<<dim3(1), dim3(1), 0, stream>>>(d_out, flags, 777.0f);
    if (need > ws_size){
        sentinel_kernel<<<dim3(1), dim3(1), 0, stream>>>(d_out, flags, 555.0f);
        return;
    }

    zero3<<<dim3((N + 255) / 256), dim3(256), 0, stream>>>(cnt, fill, pool, N);
    hist_kernel<<<dim3((E + 255) / 256), dim3(256), 0, stream>>>(ei, cnt, E, flags);
    scanA<<<dim3(nb), dim3(1024), 0, stream>>>(cnt, off, partial, N);
    scanB<<<dim3(1), dim3(64), 0, stream>>>(partial, off, nb, N);
    scanC<<<dim3(nb), dim3(1024), 0, stream>>>(off, partial, N);
    scatter_kernel<<<dim3((E + 255) / 256), dim3(256), 0, stream>>>(ei, ea, off, fill,
                                                                    srcS, eaS, E, flags);
    for (int i = 0; i < 3; i++){
        prep_b<<<dim3(Kin[i]), dim3(256), 0, stream>>>(Wl[i], BtH[i], BtL[i],
                                                       Kin[i], flags, &flags[8 + i]);
        prep_b<<<dim3(Kin[i]), dim3(256), 0, stream>>>(Wr[i], BtH[i] + (size_t)256 * Kin[i],
                                                       BtL[i] + (size_t)256 * Kin[i],
                                                       Kin[i], flags, &flags[8 + i]);
    }
    DJobs jobs;
    for (int i = 0; i < 3; i++){
        jobs.j[i]     = { We[i], WeF  + i * 256, 256 };
        jobs.j[3 + i] = { at[i], attF + i * 256, 256 };
        jobs.j[6 + i] = { bb[i], bbF  + i * 256, 256 };
    }
    jobs.j[9]  = { Wh1, Wh1F, 2560 };
    jobs.j[10] = { bh1, bh1F, 10 };
    jobs.j[11] = { Wh2, Wh2F, 10 };
    jobs.j[12] = { bh2, bh2F, 1 };
    decode_many<<<dim3(13), dim3(256), 0, stream>>>(jobs, flags);

    dim3 gemm_grid((N + 127) / 128, 4);
    for (int L = 0; L < 3; L++){
        const void* A = (L == 0) ? feat : (const void*)QHi;
        int aRaw = (L == 0) ? 1 : 0;
        gemm_tpl<1><<<gemm_grid, dim3(256), 0, stream>>>(A, QLo, aRaw, BtH[L], BtL[L],
                                                         PR, N, Kin[L], flags, &flags[8 + L]);
        gemm_tpl<0><<<gemm_grid, dim3(256), 0, stream>>>(A, QLo, aRaw, BtH[L], BtL[L],
                                                         PR, N, Kin[L], flags, &flags[8 + L]);
        fused_agg<<<dim3((N + 3) / 4), dim3(256), 0, stream>>>(PR, srcS, eaS, off,
                                                               WeF + L * 256, attF + L * 256,
                                                               bbF + L * 256, QHi, QLo, N);
    }
    col_max2<<<dim3(256), dim3(256), 0, stream>>>(QHi, QLo, pool, N);
    head_kernel<<<dim3(1), dim3(64), 0, stream>>>(pool, Wh1F, bh1F, Wh2F, bh2F, d_out, flags);
    (void)n_in; (void)out_size;
}